// Round 1
// baseline (242.975 us; speedup 1.0000x reference)
//
#include <hip/hip_runtime.h>
#include <math.h>

// Problem shape (fixed by the reference): x is [B=8, S=4096, D=1024] fp32.
constexpr int B = 8;
constexpr int S = 4096;
constexpr int D = 1024;
constexpr int DQ = D / 4;          // float4 groups per row = 256 (pow2)
constexpr int DQ_SHIFT = 8;        // log2(DQ)
constexpr int PLANE4 = S * DQ;     // float4 elements in one [S,D] plane

// -log2(10000) / D
#define NEG_L2_10000_OVER_D (-13.287712379549449f / 1024.0f)

__global__ __launch_bounds__(256)
void pe_add_kernel(const float* __restrict__ x, float* __restrict__ out) {
    const int idx4 = blockIdx.x * blockDim.x + threadIdx.x;   // 0 .. PLANE4-1
    if (idx4 >= PLANE4) return;

    const int dq = idx4 & (DQ - 1);       // which float4 within the row
    const int s  = idx4 >> DQ_SHIFT;      // sequence position
    const int d0 = dq << 2;               // first dim index (multiple of 4)

    const float fs = (float)s;

    // inv_wave_j = 10000^(-(d0+j)/D) ; angle_j = s * inv_wave_j
    const float a0 = fs * exp2f((float)(d0 + 0) * NEG_L2_10000_OVER_D);
    const float a1 = fs * exp2f((float)(d0 + 1) * NEG_L2_10000_OVER_D);
    const float a2 = fs * exp2f((float)(d0 + 2) * NEG_L2_10000_OVER_D);
    const float a3 = fs * exp2f((float)(d0 + 3) * NEG_L2_10000_OVER_D);

    float4 pe;
    pe.x = sinf(a0);   // d0+0 even -> sin
    pe.y = cosf(a1);   // odd  -> cos
    pe.z = sinf(a2);
    pe.w = cosf(a3);

    const float4* __restrict__ xv = (const float4*)x;
    float4* __restrict__ ov = (float4*)out;

#pragma unroll
    for (int b = 0; b < B; ++b) {
        const size_t off = (size_t)b * PLANE4 + idx4;
        float4 v = xv[off];
        v.x += pe.x;
        v.y += pe.y;
        v.z += pe.z;
        v.w += pe.w;
        ov[off] = v;
    }
}

extern "C" void kernel_launch(void* const* d_in, const int* in_sizes, int n_in,
                              void* d_out, int out_size, void* d_ws, size_t ws_size,
                              hipStream_t stream) {
    const float* x = (const float*)d_in[0];
    float* out = (float*)d_out;

    const int threads = 256;
    const int blocks = (PLANE4 + threads - 1) / threads;   // 4096
    pe_add_kernel<<<blocks, threads, 0, stream>>>(x, out);
}

// Round 2
// 219.270 us; speedup vs baseline: 1.1081x; 1.1081x over previous
//
#include <hip/hip_runtime.h>
#include <math.h>

// Problem shape (fixed by the reference): x is [B=8, S=4096, D=1024] fp32.
constexpr int B = 8;
constexpr int S = 4096;
constexpr int D = 1024;
constexpr int DQ = D / 4;            // float4 groups per row = 256
constexpr int DQ_SHIFT = 8;          // log2(DQ)
constexpr int PLANE4 = S * DQ;       // 2^20 float4 per [S,D] plane
constexpr int TOTAL4 = B * PLANE4;   // 2^23 float4 total

// -log2(10000) / D
#define NEG_L2_10000_OVER_D (-13.287712379549449f / 1024.0f)

__global__ __launch_bounds__(256)
void pe_add_kernel(const float* __restrict__ x, float* __restrict__ out) {
    const int idx4 = blockIdx.x * blockDim.x + threadIdx.x;  // 0 .. TOTAL4-1

    // Issue the load first so its latency overlaps the pe computation.
    const float4* __restrict__ xv = (const float4*)x;
    float4* __restrict__ ov = (float4*)out;
    float4 v = xv[idx4];

    const int pidx = idx4 & (PLANE4 - 1);   // position within the [S,D] plane
    const int dq   = pidx & (DQ - 1);
    const int s    = pidx >> DQ_SHIFT;
    const int d0   = dq << 2;

    const float fs = (float)s;
    const float a0 = fs * exp2f((float)(d0 + 0) * NEG_L2_10000_OVER_D);
    const float a1 = fs * exp2f((float)(d0 + 1) * NEG_L2_10000_OVER_D);
    const float a2 = fs * exp2f((float)(d0 + 2) * NEG_L2_10000_OVER_D);
    const float a3 = fs * exp2f((float)(d0 + 3) * NEG_L2_10000_OVER_D);

    v.x += __sinf(a0);   // even dim -> sin
    v.y += __cosf(a1);   // odd  dim -> cos
    v.z += __sinf(a2);
    v.w += __cosf(a3);

    ov[idx4] = v;
}

extern "C" void kernel_launch(void* const* d_in, const int* in_sizes, int n_in,
                              void* d_out, int out_size, void* d_ws, size_t ws_size,
                              hipStream_t stream) {
    const float* x = (const float*)d_in[0];
    float* out = (float*)d_out;

    const int threads = 256;
    const int blocks = TOTAL4 / threads;   // 32768
    pe_add_kernel<<<blocks, threads, 0, stream>>>(x, out);
}